// Round 1
// 2695.177 us; speedup vs baseline: 1.0475x; 1.0475x over previous
//
#include <hip/hip_runtime.h>

#define T_STEPS 512
#define B_SZ    128
#define H_SZ    1024

typedef __bf16 bf16x8 __attribute__((ext_vector_type(8)));
typedef float  f32x4  __attribute__((ext_vector_type(4)));
typedef float  f32x2  __attribute__((ext_vector_type(2)));

__device__ __forceinline__ void split_bf16(float x, __bf16& hi, __bf16& lo) {
  hi = (__bf16)x;
  lo = (__bf16)(x - (float)hi);
}

// Write-through ops (sc0 sc1): bypass L1/L2 to the agent coherence point
// (Infinity Cache). Inline asm is NOT tracked by the compiler waitcnt pass --
// pair with explicit s_waitcnt vmcnt(0).
__device__ __forceinline__ void store_dword_wt(float* p, float v) {
  asm volatile("global_store_dword %0, %1, off sc0 sc1" :: "v"(p), "v"(v) : "memory");
}
__device__ __forceinline__ void store_short_wt(__bf16* p, __bf16 v) {
  unsigned int bits = (unsigned int)__builtin_bit_cast(unsigned short, v);
  asm volatile("global_store_short %0, %1, off sc0 sc1" :: "v"(p), "v"(bits) : "memory");
}
// LLC-coherent 16B load: ring slots are reused every 2 steps, so consumer
// L1/L2 can hold stale copies -- plain cached loads are NOT safe here.
__device__ __forceinline__ f32x4 load_x4_wt(const __bf16* p) {
  f32x4 r;
  asm volatile("global_load_dwordx4 %0, %1, off sc0 sc1" : "=v"(r) : "v"(p) : "memory");
  return r;
}
__device__ __forceinline__ void wait_vm0() {
  asm volatile("s_waitcnt vmcnt(0)" ::: "memory");
}

// 256 WGs x 512 threads (8 waves), persistent. 8 groups (16 batches) x 32
// column slices (32 cols). K split 8 ways across waves (K=128/wave).
// PRESPLIT=true: producers publish relu'd, bf16-hi/lo-split state planes into
// a 2-slot workspace ring (write-through); consumers load MFMA A-fragments
// directly via LLC-coherent 16B loads -- zero convert VALU on the critical
// path. PRESPLIT=false fallback (small ws): v1-style f32 state via `out`
// (write-through, never-reused addresses -> plain cached consumer loads OK).
template<bool PRESPLIT>
__global__ __launch_bounds__(512, 2)
void rnn_scan_kernel(const float* __restrict__ inputs,
                     const float* __restrict__ init_state,
                     const float* __restrict__ noise,
                     const float* __restrict__ wih,
                     const float* __restrict__ whh,
                     const float* __restrict__ bias,
                     float* __restrict__ out,
                     unsigned int* __restrict__ flags,
                     __bf16* __restrict__ planes) {
  constexpr float kAlpha = 0.2f;
  constexpr float kBeta  = 0.8f;
  constexpr float kSigma = 0.15811388300841897f;  // sqrt(2/alpha)*0.05
  constexpr int   kPlane = B_SZ * H_SZ;           // elements per plane

  const int wg   = blockIdx.x;
  const int g    = wg & 7;    // group: blockIdx%8 -> XCD-affine if round-robin
  const int s    = wg >> 3;   // column slice 0..31
  const int b0   = g << 4;    // first batch of group
  const int j0   = s << 5;    // first column of slice
  const int tid  = threadIdx.x;
  const int wave = tid >> 6;          // 0..7, owns K in [wave*128, wave*128+128)
  const int lane = tid & 63;
  const int jn   = lane & 15;         // MFMA m/n lane index
  const int kq   = (lane >> 4) << 3;  // MFMA k quad offset 0/8/16/24

  __shared__ float cred[8][2][16][17];  // per-wave partial C, padded

  // update-phase mapping: one state element per thread
  const int b_l = tid >> 5;        // 0..15
  const int jc  = tid & 31;        // 0..31
  const int j   = j0 + jc;
  const int gb  = b0 + b_l;

  const float w0 = wih[j];
  const float w1 = wih[H_SZ + j];
  const float bi = bias[j];

  // state kept in a register for this thread's element
  float h = init_state[gb * H_SZ + j];
  if constexpr (PRESPLIT) {
    out[gb * H_SZ + j] = h;  // plain: nothing reads `out` in this mode
    float r = fmaxf(h, 0.f);
    __bf16 hh, ll; split_bf16(r, hh, ll);
    store_short_wt(planes + 0 * kPlane + gb * H_SZ + j, hh);  // slot0 hi
    store_short_wt(planes + 1 * kPlane + gb * H_SZ + j, ll);  // slot0 lo
  } else {
    store_dword_wt(&out[gb * H_SZ + j], h);
  }

  // ---- static B fragments: W_hh[k in wave's 128-range][32 cols], hi/lo ----
  bf16x8 Bh[4][2], Bl[4][2];
  #pragma unroll
  for (int i = 0; i < 4; ++i) {
    const int kb = (wave << 7) + (i << 5) + kq;
    #pragma unroll
    for (int jt = 0; jt < 2; ++jt) {
      const int jcB = j0 + (jt << 4) + jn;
      bf16x8 vh, vl;
      #pragma unroll
      for (int u = 0; u < 8; ++u) {
        const float wv = whh[(kb + u) * H_SZ + jcB];
        __bf16 hh, ll; split_bf16(wv, hh, ll);
        vh[u] = hh; vl[u] = ll;
      }
      Bh[i][jt] = vh; Bl[i][jt] = vl;
    }
  }

  wait_vm0();       // state-0 write-through stores acked at coherence point
  __syncthreads();
  if (tid == 0) {
    __hip_atomic_store(&flags[(g << 5) + s], 1u,
                       __ATOMIC_RELAXED, __HIP_MEMORY_SCOPE_AGENT);
  }

  const size_t BH = (size_t)B_SZ * H_SZ;

  for (int t = 0; t < T_STEPS; ++t) {
    // prefetch drive operands (state-independent) before the sync point
    float nz  = noise[t * BH + gb * H_SZ + j];
    f32x2 inp = *(const f32x2*)&inputs[(t * B_SZ + gb) * 2];

    // per-wave wait: this wave's K window [wave*128, +128) is produced by
    // slices 4*wave .. 4*wave+3 only -- poll just those 4 flags so early
    // waves start loads/MFMA while the stragglers are still publishing.
    {
      const unsigned int target = (unsigned int)(t + 1);
      int spins = 0;
      bool ok;
      do {
        unsigned int v = target;
        if (lane < 4)
          v = __hip_atomic_load(&flags[(g << 5) + (wave << 2) + lane],
                                __ATOMIC_RELAXED, __HIP_MEMORY_SCOPE_AGENT);
        ok = __all(v >= target);
        if (!ok) { __builtin_amdgcn_s_sleep(1); if (++spins > (1 << 24)) break; }
      } while (!ok);
    }
    asm volatile("" ::: "memory");  // don't hoist A loads above the spin

    f32x4 acc0 = {0.f, 0.f, 0.f, 0.f}, acc1 = {0.f, 0.f, 0.f, 0.f};

    if constexpr (PRESPLIT) {
      // direct pre-split fragment loads: zero convert VALU
      const __bf16* hp = planes + (size_t)((t & 1) << 1) * kPlane;
      const __bf16* lp = hp + kPlane;
      const int rowoff = (b0 + jn) * H_SZ + (wave << 7) + kq;
      f32x4 ahr[4], alr[4];
      #pragma unroll
      for (int i = 0; i < 4; ++i) {
        ahr[i] = load_x4_wt(hp + rowoff + (i << 5));
        alr[i] = load_x4_wt(lp + rowoff + (i << 5));
      }
      wait_vm0();
      __builtin_amdgcn_sched_barrier(0);  // rule #18: keep MFMAs below the wait
      #pragma unroll
      for (int i = 0; i < 4; ++i) {
        bf16x8 ah = __builtin_bit_cast(bf16x8, ahr[i]);
        bf16x8 al = __builtin_bit_cast(bf16x8, alr[i]);
        acc0 = __builtin_amdgcn_mfma_f32_16x16x32_bf16(ah, Bh[i][0], acc0, 0, 0, 0);
        acc1 = __builtin_amdgcn_mfma_f32_16x16x32_bf16(ah, Bh[i][1], acc1, 0, 0, 0);
        acc0 = __builtin_amdgcn_mfma_f32_16x16x32_bf16(al, Bh[i][0], acc0, 0, 0, 0);
        acc1 = __builtin_amdgcn_mfma_f32_16x16x32_bf16(al, Bh[i][1], acc1, 0, 0, 0);
        acc0 = __builtin_amdgcn_mfma_f32_16x16x32_bf16(ah, Bl[i][0], acc0, 0, 0, 0);
        acc1 = __builtin_amdgcn_mfma_f32_16x16x32_bf16(ah, Bl[i][1], acc1, 0, 0, 0);
      }
    } else {
      // fallback: f32 state rows from `out` (fresh lines -> cached loads OK)
      const float* arow = out + t * BH + (size_t)(b0 + jn) * H_SZ + (wave << 7) + kq;
      #pragma unroll
      for (int i = 0; i < 4; ++i) {
        f32x4 v0 = *(const f32x4*)(arow + (i << 5));
        f32x4 v1 = *(const f32x4*)(arow + (i << 5) + 4);
        bf16x8 ah, al;
        #pragma unroll
        for (int u = 0; u < 4; ++u) {
          const float r0 = fmaxf(v0[u], 0.f);
          const float r1 = fmaxf(v1[u], 0.f);
          __bf16 h0, l0, h1, l1;
          split_bf16(r0, h0, l0); split_bf16(r1, h1, l1);
          ah[u] = h0; al[u] = l0; ah[u + 4] = h1; al[u + 4] = l1;
        }
        acc0 = __builtin_amdgcn_mfma_f32_16x16x32_bf16(ah, Bh[i][0], acc0, 0, 0, 0);
        acc1 = __builtin_amdgcn_mfma_f32_16x16x32_bf16(ah, Bh[i][1], acc1, 0, 0, 0);
        acc0 = __builtin_amdgcn_mfma_f32_16x16x32_bf16(al, Bh[i][0], acc0, 0, 0, 0);
        acc1 = __builtin_amdgcn_mfma_f32_16x16x32_bf16(al, Bh[i][1], acc1, 0, 0, 0);
        acc0 = __builtin_amdgcn_mfma_f32_16x16x32_bf16(ah, Bl[i][0], acc0, 0, 0, 0);
        acc1 = __builtin_amdgcn_mfma_f32_16x16x32_bf16(ah, Bl[i][1], acc1, 0, 0, 0);
      }
    }

    // ---- 8-wave reduction via LDS ----
    #pragma unroll
    for (int r = 0; r < 4; ++r) {
      const int br = ((lane >> 4) << 2) + r;  // C row = batch
      cred[wave][0][br][jn] = acc0[r];
      cred[wave][1][br][jn] = acc1[r];
    }
    __syncthreads();

    // ---- state update for this thread's (b_l, j) ----
    const int tile = jc >> 4;
    const int c    = jc & 15;
    const float a = cred[0][tile][b_l][c] + cred[1][tile][b_l][c]
                  + cred[2][tile][b_l][c] + cred[3][tile][b_l][c]
                  + cred[4][tile][b_l][c] + cred[5][tile][b_l][c]
                  + cred[6][tile][b_l][c] + cred[7][tile][b_l][c];
    const float d = fmaf(inp[0], w0, fmaf(inp[1], w1, fmaf(kSigma, nz, bi)));
    h = kBeta * h + kAlpha * (a + d);

    if constexpr (PRESPLIT) {
      out[(t + 1) * BH + gb * H_SZ + j] = h;  // plain: final answer only
      float r = fmaxf(h, 0.f);
      __bf16 hh, ll; split_bf16(r, hh, ll);
      __bf16* hp = planes + (size_t)(((t + 1) & 1) << 1) * kPlane;
      store_short_wt(hp + gb * H_SZ + j, hh);
      store_short_wt(hp + kPlane + gb * H_SZ + j, ll);
    } else {
      store_dword_wt(&out[(t + 1) * BH + gb * H_SZ + j], h);
    }

    wait_vm0();       // this thread's state stores acked at coherence point
    __syncthreads();  // all threads stored + cred reads done
    if (tid == 0) {
      __hip_atomic_store(&flags[(g << 5) + s], (unsigned int)(t + 2),
                         __ATOMIC_RELAXED, __HIP_MEMORY_SCOPE_AGENT);
    }
  }
}

extern "C" void kernel_launch(void* const* d_in, const int* in_sizes, int n_in,
                              void* d_out, int out_size, void* d_ws, size_t ws_size,
                              hipStream_t stream) {
  const float* inputs     = (const float*)d_in[0];
  const float* init_state = (const float*)d_in[1];
  const float* noise      = (const float*)d_in[2];
  const float* wih        = (const float*)d_in[3];
  const float* whh        = (const float*)d_in[4];
  const float* bias       = (const float*)d_in[5];
  float* out = (float*)d_out;
  unsigned int* flags = (unsigned int*)d_ws;  // 8 groups x 32 slices

  // d_ws is poisoned 0xAA before every launch; flags must start at 0
  hipMemsetAsync(flags, 0, 256 * sizeof(unsigned int), stream);

  // ring: 2 slots x {hi,lo} planes x B x H bf16, after a 4 KiB flag page
  const size_t need = 4096 + (size_t)2 * 2 * B_SZ * H_SZ * sizeof(__bf16);
  if (ws_size >= need) {
    __bf16* planes = (__bf16*)((char*)d_ws + 4096);
    rnn_scan_kernel<true><<<dim3(256), dim3(512), 0, stream>>>(
        inputs, init_state, noise, wih, whh, bias, out, flags, planes);
  } else {
    rnn_scan_kernel<false><<<dim3(256), dim3(512), 0, stream>>>(
        inputs, init_state, noise, wih, whh, bias, out, flags, (__bf16*)nullptr);
  }
}